// Round 11
// baseline (1898.985 us; speedup 1.0000x reference)
//
#include <hip/hip_runtime.h>
#include <math.h>

#define N_NODES 20000
#define N_EDGES 320000
#define N_GRAPHS 64
#define PD 9
#define KD 32
#define MD 32
#define NK 5
#define EIN 161
#define EIN2 322
#define ALLF (KD*(NK+1))   // 192
#define LN_EPS 1e-5f

typedef __attribute__((ext_vector_type(8))) short short8;
typedef __attribute__((ext_vector_type(4))) float f32x4;
typedef __attribute__((ext_vector_type(16))) float f32x16;
typedef __attribute__((ext_vector_type(4))) unsigned u32x4;
typedef __attribute__((ext_vector_type(2))) unsigned u32x2;

__device__ __forceinline__ float silu_f(float x) { return x / (1.f + __expf(-x)); }

__device__ __forceinline__ unsigned short f2bf(float x) {
    union { float f; unsigned u; } v; v.f = x;
    unsigned r = v.u + 0x7FFFu + ((v.u >> 16) & 1u);
    return (unsigned short)(r >> 16);
}

__device__ __forceinline__ unsigned cvt_pk_bf16(float lo, float hi) {
    unsigned r;
    asm("v_cvt_pk_bf16_f32 %0, %1, %2" : "=v"(r) : "v"(lo), "v"(hi));
    return r;
}

// ---------------- W1 pack for 32x32x16, permuted, bias+rel folded ----------------
// Packed K (176 = 11 steps of 16): k<128 -> orig k; 128..159 -> orig k+1 (skip
// rel row 128); k==160 -> const-1 row = eb1; k==161 -> rel row (orig 128); else 0.
// M permutation within tile m: permuted row p=4h+c+8b (h=(p>>2)&1,c=p&3,b=p>>3)
// -> orig col n = 32m + 16*(b>>1) + 8h + c + 4*(b&1). This makes GEMM1 D regs
// 0..7 / 8..15 be exactly GEMM2's B-frags for k-steps 2m / 2m+1.
// Layout: [kk][m(11)][s(11)][lane(64)][i(8)]
__global__ __launch_bounds__(256) void pack_w1_kernel(
    const float* __restrict__ eW1, const float* __restrict__ eb1,
    unsigned short* __restrict__ W1p)
{
    int fid = blockIdx.x * 256 + threadIdx.x;
    if (fid >= NK*11*11*64) return;
    int kk = fid / (11*11*64);
    int r  = fid % (11*11*64);
    int m  = r / (11*64);
    int r2 = r % (11*64);
    int s  = r2 >> 6;
    int l  = r2 & 63;
    int p = l & 31, khalf = l >> 5;
    int h = (p >> 2) & 1, c = p & 3, bb = p >> 3;
    int n = 32*m + 16*(bb >> 1) + 8*h + c + 4*(bb & 1);
    short8 out;
    #pragma unroll
    for (int i = 0; i < 8; ++i) {
        int k = 16*s + 8*khalf + i;
        float v = 0.f;
        if (n < EIN2) {
            if (k < 128)       v = eW1[((size_t)kk*EIN + k)*EIN2 + n];
            else if (k < 160)  v = eW1[((size_t)kk*EIN + k + 1)*EIN2 + n];
            else if (k == 160) v = eb1[(size_t)kk*EIN2 + n];
            else if (k == 161) v = eW1[((size_t)kk*EIN + 128)*EIN2 + n];
        }
        out[i] = (short)f2bf(v);
    }
    *(short8*)&W1p[(size_t)fid*8] = out;
}

// W2 pack for 32x32x16: [kk][s2(22)][lane][i]; lane: out-col = l&31,
// k2 = 16*s2 + 8*(l>>5) + i (rows >= 322 zero).
__global__ __launch_bounds__(256) void pack_w2_kernel(
    const float* __restrict__ eW2, unsigned short* __restrict__ W2p)
{
    int fid = blockIdx.x * 256 + threadIdx.x;
    if (fid >= NK*22*64) return;
    int kk = fid / (22*64);
    int r  = fid % (22*64);
    int s2 = r >> 6;
    int l  = r & 63;
    int n = l & 31, khalf = l >> 5;
    short8 out;
    #pragma unroll
    for (int i = 0; i < 8; ++i) {
        int k2 = 16*s2 + 8*khalf + i;
        float v = (k2 < EIN2) ? eW2[((size_t)kk*EIN2 + k2)*MD + n] : 0.f;
        out[i] = (short)f2bf(v);
    }
    *(short8*)&W2p[(size_t)fid*8] = out;
}

// node weights (16x16x32 path, unchanged): W1A permuted; W2A plain.
__global__ __launch_bounds__(256) void pack_nw_kernel(
    const float* __restrict__ nW1, const float* __restrict__ nW2,
    unsigned short* __restrict__ W1A, unsigned short* __restrict__ W2A)
{
    int fid = blockIdx.x * 256 + threadIdx.x;
    const int tot1 = NK*4*2*64;
    const int tot2 = NK*2*2*64;
    if (fid < tot1) {
        int kk = fid / (4*2*64);
        int r  = fid % (4*2*64);
        int mt = r / 128;
        int r2 = r % 128;
        int kb = r2 >> 6;
        int l  = r2 & 63;
        int q = l >> 4, el = l & 15;
        int n = 32*(mt >> 1) + 8*(el >> 2) + 4*(mt & 1) + (el & 3);  // permuted
        short8 out;
        #pragma unroll
        for (int i = 0; i < 8; ++i)
            out[i] = (short)f2bf(nW1[((size_t)kk*64 + 32*kb + 8*q + i)*64 + n]);
        *(short8*)&W1A[(size_t)fid*8] = out;
    } else if (fid < tot1 + tot2) {
        int f2 = fid - tot1;
        int kk = f2 / (2*2*64);
        int r  = f2 % (2*2*64);
        int mt2 = r / 128;
        int r2  = r % 128;
        int kb  = r2 >> 6;
        int l   = r2 & 63;
        int q = l >> 4, el = l & 15;
        short8 out;
        #pragma unroll
        for (int i = 0; i < 8; ++i)
            out[i] = (short)f2bf(nW2[((size_t)kk*64 + 32*kb + 8*q + i)*32 + 16*mt2 + el]);
        *(short8*)&W2A[(size_t)f2*8] = out;
    }
}

// ---------------- node embed ----------------
__global__ __launch_bounds__(256) void embed_nodes_kernel(
    const float* __restrict__ props, const float* __restrict__ W,
    const float* __restrict__ b,
    float* __restrict__ feats, unsigned short* __restrict__ feats_bf,
    float* __restrict__ allf)
{
    int t = threadIdx.x;
    int n = blockIdx.x * 8 + (t >> 5);
    int f = t & 31;
    if (n >= N_NODES) return;
    float acc = b[f];
    #pragma unroll
    for (int i = 0; i < PD; ++i) acc += props[n*PD + i] * W[i*KD + f];
    feats[n*KD + f] = acc;
    feats_bf[n*KD + f] = f2bf(acc);
    allf[(size_t)n*ALLF + f] = acc;
}

// ------- edge prep: 128 edges/block; edge embed + rel + deg + constpack -------
// constpack per (block, wave g): 6 slots of [lane64][8] bf16:
// slot = grp*2+half; grp 0 sin,1 cos,2 ef; lane (e32=l&31, hi=l>>5):
// value index within the 32-group = 16*half + 8*hi + i.
__global__ __launch_bounds__(256) void edge_prep_kernel(
    const float* __restrict__ edge_props, const float* __restrict__ positions,
    const int* __restrict__ ei, const float* __restrict__ W,
    const float* __restrict__ b, float* __restrict__ rel,
    float* __restrict__ deg, unsigned short* __restrict__ constpack)
{
    __shared__ float ef[128*32];
    __shared__ float rdl[128];
    int t = threadIdx.x;
    int b0 = blockIdx.x;
    int e0 = b0 * 128;

    {
        int e = t >> 1, sub = t & 1;          // 16 cols per thread
        float acc[16];
        #pragma unroll
        for (int j = 0; j < 16; ++j) acc[j] = b[sub*16 + j];
        #pragma unroll
        for (int i = 0; i < PD; ++i) {
            float p = edge_props[(size_t)(e0 + e)*PD + i];
            #pragma unroll
            for (int j = 0; j < 16; ++j) acc[j] += p * W[i*KD + sub*16 + j];
        }
        #pragma unroll
        for (int j = 0; j < 16; ++j) ef[e*32 + sub*16 + j] = acc[j];
    }
    if (t < 128) {
        int e = e0 + t;
        int s = ei[e], d = ei[N_EDGES + e];
        float dx = positions[s*3+0] - positions[d*3+0];
        float dy = positions[s*3+1] - positions[d*3+1];
        float dz = positions[s*3+2] - positions[d*3+2];
        float rd = dx*dx + dy*dy + dz*dz;
        rdl[t] = rd;
        rel[e] = rd;
        atomicAdd(&deg[d], 1.f);
    }
    __syncthreads();

    int l = t & 63, w = t >> 6;
    int e32 = l & 31, hi = l >> 5;
    int eloc = 32*w + e32;
    float rd = rdl[eloc];
    #pragma unroll
    for (int slot = 0; slot < 6; ++slot) {
        int grp = slot >> 1, half = slot & 1;
        short8 out;
        #pragma unroll
        for (int i = 0; i < 8; ++i) {
            int off = 16*half + 8*hi + i;     // 0..31 within group
            float v;
            if (grp == 0)      v = sinf(ldexpf(rd, -off));
            else if (grp == 1) v = cosf(ldexpf(rd, -off));
            else               v = ef[eloc*32 + off];
            out[i] = (short)f2bf(v);
        }
        *(short8*)&constpack[(((size_t)b0*4 + w)*6 + slot)*512 + (size_t)l*8] = out;
    }
}

// ---------------- MFMA edge MLP: 32x32x16, 32 edges/wave, 128/block ----------------
// GEMM1: D[336p,32e] = W1perm x h, K=176 (bias+rel folded). Permutation makes
// D regs 0..7 / 8..15 be GEMM2 B-frags for k-steps 2m/2m+1 directly.
// GEMM2: m_ij[32ch,32e] = W2 x h1, K=352. No LDS, no barriers, no lane exchange.
__global__ __launch_bounds__(256) void edge_mlp_mfma(
    const unsigned short* __restrict__ feats_bf,
    const unsigned short* __restrict__ constpack,
    const float* __restrict__ rel, const int* __restrict__ ei,
    const unsigned short* __restrict__ W1p, const unsigned short* __restrict__ W2p,
    const float* __restrict__ eb2, const float* __restrict__ lg,
    const float* __restrict__ lb, float* __restrict__ msum)
{
    int t = threadIdx.x;
    int b = blockIdx.x;
    int w = t >> 6, l = t & 63, e32 = l & 31, hi = l >> 5;
    int edge = b*128 + 32*w + e32;
    int srcn = ei[edge];
    int dstn = ei[N_EDGES + edge];
    float rd = rel[edge];

    // B-frags: lane holds its edge's k-slice 8*hi..+7 of each 16-step
    short8 bf[11];
    bf[0] = *(const short8*)&feats_bf[(size_t)dstn*KD + 8*hi];
    bf[1] = *(const short8*)&feats_bf[(size_t)dstn*KD + 16 + 8*hi];
    bf[2] = *(const short8*)&feats_bf[(size_t)srcn*KD + 8*hi];
    bf[3] = *(const short8*)&feats_bf[(size_t)srcn*KD + 16 + 8*hi];
    const unsigned short* cp = &constpack[(((size_t)b*4 + w)*6)*512 + (size_t)l*8];
    #pragma unroll
    for (int slot = 0; slot < 6; ++slot)
        bf[4 + slot] = *(const short8*)&cp[(size_t)slot*512];
    {   // k-step 10: [1.0, rd, 0...] on hi==0, zeros on hi==1
        short8 z = {0,0,0,0,0,0,0,0};
        if (hi == 0) { z[0] = (short)0x3F80; z[1] = (short)f2bf(rd); }
        bf[10] = z;
    }

    const unsigned short* w1l = W1p + (size_t)l*8;
    const unsigned short* w2l = W2p + (size_t)l*8;

    f32x16 acc2 = {0.f};
    #pragma unroll
    for (int m = 0; m < 11; ++m) {
        f32x16 acc1 = {0.f};
        #pragma unroll
        for (int s = 0; s < 11; ++s)
            acc1 = __builtin_amdgcn_mfma_f32_32x32x16_bf16(
                *(const short8*)&w1l[(size_t)(m*11 + s)*512], bf[s], acc1, 0, 0, 0);
        // silu (bias already folded) -> pack regs 0..7 / 8..15
        unsigned plo[4], phi[4];
        #pragma unroll
        for (int j = 0; j < 4; ++j) {
            plo[j] = cvt_pk_bf16(silu_f(acc1[2*j]),     silu_f(acc1[2*j+1]));
            phi[j] = cvt_pk_bf16(silu_f(acc1[8+2*j]),   silu_f(acc1[8+2*j+1]));
        }
        u32x4 vlo = { plo[0], plo[1], plo[2], plo[3] };
        u32x4 vhi = { phi[0], phi[1], phi[2], phi[3] };
        acc2 = __builtin_amdgcn_mfma_f32_32x32x16_bf16(
            *(const short8*)&w2l[(size_t)(2*m)*512],
            __builtin_bit_cast(short8, vlo), acc2, 0, 0, 0);
        acc2 = __builtin_amdgcn_mfma_f32_32x32x16_bf16(
            *(const short8*)&w2l[(size_t)(2*m + 1)*512],
            __builtin_bit_cast(short8, vhi), acc2, 0, 0, 0);
    }

    // epilogue: lane holds 16 of 32 channels for ITS edge (ch=(r&3)+8*(r>>2)+4hi)
    float mv[16];
    float ssum = 0.f;
    #pragma unroll
    for (int rg = 0; rg < 4; ++rg) {
        f32x4 e2 = *(const f32x4*)&eb2[8*rg + 4*hi];
        #pragma unroll
        for (int c = 0; c < 4; ++c) {
            float v = silu_f(acc2[rg*4 + c] + e2[c]);
            mv[rg*4 + c] = v;
            ssum += v;
        }
    }
    ssum += __shfl_xor(ssum, 32);
    float mu = ssum * (1.f/32.f);
    float vsum = 0.f;
    #pragma unroll
    for (int r = 0; r < 16; ++r) { float d = mv[r] - mu; vsum += d*d; }
    vsum += __shfl_xor(vsum, 32);
    float rs = rsqrtf(vsum * (1.f/32.f) + LN_EPS);

    float* mrow = &msum[(size_t)dstn*MD];
    #pragma unroll
    for (int rg = 0; rg < 4; ++rg) {
        int ch0 = 8*rg + 4*hi;
        f32x4 gv = *(const f32x4*)&lg[ch0];
        f32x4 bv = *(const f32x4*)&lb[ch0];
        #pragma unroll
        for (int c = 0; c < 4; ++c)
            atomicAdd(&mrow[ch0 + c], (mv[rg*4 + c] - mu)*rs*gv[c] + bv[c]);
    }
}

// ---------------- MFMA node MLP: 64 nodes/block, 16/wave, shuffle-free ----------------
__global__ __launch_bounds__(256) void node_mlp_mfma(
    const float* __restrict__ msum, const float* __restrict__ deg,
    const unsigned short* __restrict__ W1A, const unsigned short* __restrict__ W2A,
    const float* __restrict__ nb1, const float* __restrict__ nb2,
    const float* __restrict__ eln_g, const float* __restrict__ eln_b,
    const float* __restrict__ n1g, const float* __restrict__ n1b,
    const float* __restrict__ n2g, const float* __restrict__ n2b,
    float* __restrict__ feats, unsigned short* __restrict__ feats_bf,
    float* __restrict__ allf, int kslot)
{
    int t = threadIdx.x;
    int w = t >> 6, l = t & 63, q = l >> 4, el = l & 15;
    int nd = blockIdx.x*64 + 16*w + el;
    bool okn = nd < N_NODES;
    size_t ndc = okn ? (size_t)nd : (size_t)(N_NODES - 1);

    float x[2][8];
    {
        f32x4 f0 = *(const f32x4*)&feats[ndc*KD + 8*q];
        f32x4 f1 = *(const f32x4*)&feats[ndc*KD + 8*q + 4];
        float inv = 1.f / fmaxf(deg[ndc], 1.f);
        f32x4 m0 = *(const f32x4*)&msum[ndc*KD + 8*q];
        f32x4 m1 = *(const f32x4*)&msum[ndc*KD + 8*q + 4];
        #pragma unroll
        for (int j = 0; j < 4; ++j) {
            x[0][j] = f0[j]; x[0][4+j] = f1[j];
            x[1][j] = m0[j]*inv; x[1][4+j] = m1[j]*inv;
        }
    }
    short8 xf[2];
    #pragma unroll
    for (int kb = 0; kb < 2; ++kb) {
        float s = 0.f;
        #pragma unroll
        for (int i = 0; i < 8; ++i) s += x[kb][i];
        s += __shfl_xor(s, 16); s += __shfl_xor(s, 32);
        float mu = s * (1.f/32.f);
        float vv = 0.f;
        #pragma unroll
        for (int i = 0; i < 8; ++i) { float d = x[kb][i] - mu; vv += d*d; }
        vv += __shfl_xor(vv, 16); vv += __shfl_xor(vv, 32);
        float rs = rsqrtf(vv * (1.f/32.f) + LN_EPS);
        const float* gp = kb ? eln_g : n1g;
        const float* bp = kb ? eln_b : n1b;
        f32x4 ga = *(const f32x4*)&gp[8*q];
        f32x4 gb = *(const f32x4*)&gp[8*q + 4];
        f32x4 ba = *(const f32x4*)&bp[8*q];
        f32x4 bb = *(const f32x4*)&bp[8*q + 4];
        float z[8];
        #pragma unroll
        for (int j = 0; j < 4; ++j) {
            z[j]   = (x[kb][j]   - mu)*rs*ga[j] + ba[j];
            z[4+j] = (x[kb][4+j] - mu)*rs*gb[j] + bb[j];
        }
        u32x4 pv = { cvt_pk_bf16(z[0], z[1]), cvt_pk_bf16(z[2], z[3]),
                     cvt_pk_bf16(z[4], z[5]), cvt_pk_bf16(z[6], z[7]) };
        xf[kb] = __builtin_bit_cast(short8, pv);
    }

    unsigned hr[8];
    #pragma unroll
    for (int mt = 0; mt < 4; ++mt) {
        f32x4 acc = {0.f, 0.f, 0.f, 0.f};
        acc = __builtin_amdgcn_mfma_f32_16x16x32_bf16(
            *(const short8*)&W1A[(size_t)(mt*2 + 0)*512 + (size_t)l*8], xf[0], acc, 0, 0, 0);
        acc = __builtin_amdgcn_mfma_f32_16x16x32_bf16(
            *(const short8*)&W1A[(size_t)(mt*2 + 1)*512 + (size_t)l*8], xf[1], acc, 0, 0, 0);
        int base = 32*(mt >> 1) + 4*(mt & 1) + 8*q;
        f32x4 b1v = *(const f32x4*)&nb1[base];
        float vj[4];
        #pragma unroll
        for (int j = 0; j < 4; ++j) vj[j] = silu_f(acc[j] + b1v[j]);
        int ix = (mt >> 1)*4 + (mt & 1)*2;
        hr[ix]     = cvt_pk_bf16(vj[0], vj[1]);
        hr[ix + 1] = cvt_pk_bf16(vj[2], vj[3]);
    }

    u32x4 h0v = { hr[0], hr[1], hr[2], hr[3] };
    u32x4 h1v = { hr[4], hr[5], hr[6], hr[7] };
    short8 hf0 = __builtin_bit_cast(short8, h0v);
    short8 hf1 = __builtin_bit_cast(short8, h1v);
    float o[2][4];
    #pragma unroll
    for (int mt2 = 0; mt2 < 2; ++mt2) {
        f32x4 acc = {0.f, 0.f, 0.f, 0.f};
        acc = __builtin_amdgcn_mfma_f32_16x16x32_bf16(
            *(const short8*)&W2A[(size_t)(mt2*2 + 0)*512 + (size_t)l*8], hf0, acc, 0, 0, 0);
        acc = __builtin_amdgcn_mfma_f32_16x16x32_bf16(
            *(const short8*)&W2A[(size_t)(mt2*2 + 1)*512 + (size_t)l*8], hf1, acc, 0, 0, 0);
        f32x4 b2v = *(const f32x4*)&nb2[16*mt2 + 4*q];
        #pragma unroll
        for (int j = 0; j < 4; ++j) o[mt2][j] = acc[j] + b2v[j];
    }
    float s2 = 0.f;
    #pragma unroll
    for (int mt2 = 0; mt2 < 2; ++mt2)
        #pragma unroll
        for (int j = 0; j < 4; ++j) s2 += o[mt2][j];
    s2 += __shfl_xor(s2, 16); s2 += __shfl_xor(s2, 32);
    float mu2 = s2 * (1.f/32.f);
    float vv2 = 0.f;
    #pragma unroll
    for (int mt2 = 0; mt2 < 2; ++mt2)
        #pragma unroll
        for (int j = 0; j < 4; ++j) { float d = o[mt2][j] - mu2; vv2 += d*d; }
    vv2 += __shfl_xor(vv2, 16); vv2 += __shfl_xor(vv2, 32);
    float rs2 = rsqrtf(vv2 * (1.f/32.f) + LN_EPS);

    #pragma unroll
    for (int mt2 = 0; mt2 < 2; ++mt2) {
        f32x4 gv = *(const f32x4*)&n2g[16*mt2 + 4*q];
        f32x4 bv = *(const f32x4*)&n2b[16*mt2 + 4*q];
        f32x4 fold = *(const f32x4*)&feats[ndc*KD + 16*mt2 + 4*q];
        f32x4 nf;
        #pragma unroll
        for (int j = 0; j < 4; ++j)
            nf[j] = fold[j] + (o[mt2][j] - mu2)*rs2*gv[j] + bv[j];
        if (okn) {
            *(f32x4*)&feats[(size_t)nd*KD + 16*mt2 + 4*q] = nf;
            u32x2 pb = { cvt_pk_bf16(nf[0], nf[1]), cvt_pk_bf16(nf[2], nf[3]) };
            *(u32x2*)&feats_bf[(size_t)nd*KD + 16*mt2 + 4*q] = pb;
            *(f32x4*)&allf[(size_t)nd*ALLF + kslot*KD + 16*mt2 + 4*q] = nf;
        }
    }
}

// ---------------- mean pool: 4 blocks per graph, lane<->column ----------------
__global__ __launch_bounds__(256) void pool_kernel(
    const float* __restrict__ allf, const int* __restrict__ batch,
    float* __restrict__ gsum, float* __restrict__ gcnt)
{
    int b = blockIdx.x, t = threadIdx.x;
    int g = b >> 2, part = b & 3;
    int lo = 0, hi = N_NODES;
    while (lo < hi) { int m = (lo+hi) >> 1; if (batch[m] < g) lo = m+1; else hi = m; }
    int start = lo;
    hi = N_NODES;
    while (lo < hi) { int m = (lo+hi) >> 1; if (batch[m] < g+1) lo = m+1; else hi = m; }
    int end = lo;
    if (part == 0 && t == 0) gcnt[g] = (float)(end - start);
    int len = end - start;
    int chunk = (len + 3) >> 2;
    int s = start + part*chunk;
    int e = min(end, s + chunk);
    if (t < ALLF && e > s) {
        float acc = 0.f;
        for (int n = s; n < e; ++n) acc += allf[(size_t)n*ALLF + t];
        atomicAdd(&gsum[g*ALLF + t], acc);
    }
}

// ---------------- final FNN: block per graph ----------------
__global__ __launch_bounds__(256) void fnn_kernel(
    const float* __restrict__ gsum, const float* __restrict__ gcnt,
    const float* __restrict__ W0, const float* __restrict__ b0,
    const float* __restrict__ W1, const float* __restrict__ b1,
    const float* __restrict__ W2, const float* __restrict__ b2,
    const float* __restrict__ W3, const float* __restrict__ b3,
    float* __restrict__ out)
{
    __shared__ float xs[256];
    __shared__ float partial[4];
    int g = blockIdx.x, t = threadIdx.x;
    float inv = 1.f / fmaxf(gcnt[g], 1.f);
    if (t < ALLF) xs[t] = gsum[g*ALLF + t] * inv;
    __syncthreads();
    float acc = b0[t];
    for (int i = 0; i < ALLF; ++i) acc += xs[i] * W0[i*256 + t];
    acc = silu_f(acc);
    __syncthreads(); xs[t] = acc; __syncthreads();
    acc = b1[t];
    for (int i = 0; i < 256; ++i) acc += xs[i] * W1[i*256 + t];
    acc = silu_f(acc);
    __syncthreads(); xs[t] = acc; __syncthreads();
    acc = b2[t];
    for (int i = 0; i < 256; ++i) acc += xs[i] * W2[i*256 + t];
    acc = silu_f(acc);
    __syncthreads(); xs[t] = acc; __syncthreads();
    float v = xs[t] * W3[t];
    #pragma unroll
    for (int m = 32; m; m >>= 1) v += __shfl_xor(v, m, 64);
    if ((t & 63) == 0) partial[t >> 6] = v;
    __syncthreads();
    if (t == 0) out[g] = partial[0] + partial[1] + partial[2] + partial[3] + b3[0];
}

extern "C" void kernel_launch(void* const* d_in, const int* in_sizes, int n_in,
                              void* d_out, int out_size, void* d_ws, size_t ws_size,
                              hipStream_t stream) {
    const float* props      = (const float*)d_in[0];
    const float* positions  = (const float*)d_in[1];
    const float* edge_props = (const float*)d_in[2];
    const float* embed_W    = (const float*)d_in[3];
    const float* embed_b    = (const float*)d_in[4];
    const float* eeW        = (const float*)d_in[5];
    const float* eeb        = (const float*)d_in[6];
    const float* k_eW1      = (const float*)d_in[7];
    const float* k_eb1      = (const float*)d_in[8];
    const float* k_eW2      = (const float*)d_in[9];
    const float* k_eb2      = (const float*)d_in[10];
    const float* k_eln_g    = (const float*)d_in[11];
    const float* k_eln_b    = (const float*)d_in[12];
    const float* k_n1g      = (const float*)d_in[13];
    const float* k_n1b      = (const float*)d_in[14];
    const float* k_n2g      = (const float*)d_in[15];
    const float* k_n2b      = (const float*)d_in[16];
    const float* k_nW1      = (const float*)d_in[17];
    const float* k_nb1      = (const float*)d_in[18];
    const float* k_nW2      = (const float*)d_in[19];
    const float* k_nb2      = (const float*)d_in[20];
    const float* fnn_W0     = (const float*)d_in[21];
    const float* fnn_b0     = (const float*)d_in[22];
    const float* fnn_W1     = (const float*)d_in[23];
    const float* fnn_b1     = (const float*)d_in[24];
    const float* fnn_W2     = (const float*)d_in[25];
    const float* fnn_b2     = (const float*)d_in[26];
    const float* fnn_W3     = (const float*)d_in[27];
    const float* fnn_b3     = (const float*)d_in[28];
    const int*   ei         = (const int*)d_in[29];
    const int*   batch      = (const int*)d_in[30];
    float* out = (float*)d_out;

    // ---- workspace layout (bytes, 256-aligned) ----
    char* wsb = (char*)d_ws;
    size_t off = 0;
    #define WS_ALLOC(ptr_t, name, bytes) ptr_t name = (ptr_t)(wsb + off); off += (((size_t)(bytes)) + 255) & ~(size_t)255;
    WS_ALLOC(float*, feats, (size_t)N_NODES*KD*4)
    WS_ALLOC(float*, msum,  (size_t)N_NODES*KD*4)
    WS_ALLOC(float*, deg,   (size_t)N_NODES*4)
    WS_ALLOC(float*, rel,   (size_t)N_EDGES*4)
    WS_ALLOC(float*, gsum,  (size_t)N_GRAPHS*ALLF*4)
    WS_ALLOC(float*, gcnt,  (size_t)N_GRAPHS*4)
    WS_ALLOC(float*, allf,  (size_t)N_NODES*ALLF*4)
    WS_ALLOC(unsigned short*, feats_bf,  (size_t)N_NODES*KD*2)
    WS_ALLOC(unsigned short*, constpack, (size_t)2500*4*6*64*8*2)   // 61.44 MB
    WS_ALLOC(unsigned short*, W1p,  (size_t)NK*11*11*64*8*2)        // 620 KB
    WS_ALLOC(unsigned short*, W2p,  (size_t)NK*22*64*8*2)           // 113 KB
    WS_ALLOC(unsigned short*, W1An, (size_t)NK*4*2*64*8*2)
    WS_ALLOC(unsigned short*, W2An, (size_t)NK*2*2*64*8*2)
    (void)ws_size;

    hipMemsetAsync(deg,  0, (size_t)N_NODES*4, stream);
    hipMemsetAsync(gsum, 0, (size_t)N_GRAPHS*ALLF*4, stream);

    pack_w1_kernel<<<(NK*11*11*64 + 255)/256, 256, 0, stream>>>(k_eW1, k_eb1, W1p);
    pack_w2_kernel<<<(NK*22*64 + 255)/256, 256, 0, stream>>>(k_eW2, W2p);
    pack_nw_kernel<<<(NK*4*2*64 + NK*2*2*64 + 255)/256, 256, 0, stream>>>(k_nW1, k_nW2, W1An, W2An);
    embed_nodes_kernel<<<N_NODES/8, 256, 0, stream>>>(props, embed_W, embed_b,
                                                      feats, feats_bf, allf);
    edge_prep_kernel<<<N_EDGES/128, 256, 0, stream>>>(edge_props, positions, ei, eeW, eeb,
                                                      rel, deg, constpack);

    for (int k = 0; k < NK; ++k) {
        hipMemsetAsync(msum, 0, (size_t)N_NODES*KD*4, stream);
        edge_mlp_mfma<<<N_EDGES/128, 256, 0, stream>>>(
            feats_bf, constpack, rel, ei,
            W1p + (size_t)k*11*11*512, W2p + (size_t)k*22*512,
            k_eb2 + (size_t)k*MD,
            k_eln_g + (size_t)k*MD, k_eln_b + (size_t)k*MD, msum);
        node_mlp_mfma<<<(N_NODES + 63)/64, 256, 0, stream>>>(
            msum, deg,
            W1An + (size_t)k*4*2*512, W2An + (size_t)k*2*2*512,
            k_nb1 + (size_t)k*64, k_nb2 + (size_t)k*32,
            k_eln_g + (size_t)k*MD, k_eln_b + (size_t)k*MD,
            k_n1g + (size_t)k*KD, k_n1b + (size_t)k*KD,
            k_n2g + (size_t)k*KD, k_n2b + (size_t)k*KD,
            feats, feats_bf, allf, k+1);
    }

    pool_kernel<<<N_GRAPHS*4, 256, 0, stream>>>(allf, batch, gsum, gcnt);
    fnn_kernel<<<N_GRAPHS, 256, 0, stream>>>(gsum, gcnt, fnn_W0, fnn_b0, fnn_W1, fnn_b1,
                                             fnn_W2, fnn_b2, fnn_W3, fnn_b3, out);
}